// Round 9
// baseline (2499.810 us; speedup 1.0000x reference)
//
#include <hip/hip_runtime.h>
#include <hip/hip_bf16.h>
#include <cstdint>
#include <cstddef>

#define LSEQ  64
#define BATCH 2048
#define HID   1024
#define NGATE 4096
#define VOC   256
#define EMBD  50

using bf16 = __hip_bfloat16;
typedef __attribute__((ext_vector_type(8))) __bf16 bf16x8;
typedef __attribute__((ext_vector_type(4))) float  f32x4;

__device__ __forceinline__ void gload_lds16(const void* g, void* l) {
  __builtin_amdgcn_global_load_lds(
      (const __attribute__((address_space(1))) unsigned int*)g,
      (__attribute__((address_space(3))) unsigned int*)l, 16, 0, 0);
}

__device__ __forceinline__ float sigf(float x) {
  x = fminf(fmaxf(x, -30.f), 30.f);
  return 1.f / (1.f + __expf(-x));
}
__device__ __forceinline__ float tanh_f(float x) {
  x = fminf(fmaxf(x, -15.f), 15.f);
  float e = __expf(2.f * x);
  return (e - 1.f) / (e + 1.f);
}

// system-scope (cross-XCD visible) bf16 store: past L2, lands memory-side
__device__ __forceinline__ void store_h_sys(bf16* p, float v) {
  union { __hip_bfloat16 b; unsigned short u; } cv;
  cv.b = __float2bfloat16(v);
  unsigned int d = cv.u;
  asm volatile("global_store_short %0, %1, off sc0 sc1" :: "v"(p), "v"(d) : "memory");
}

// ---------------- setup kernels ----------------

__global__ void k_prep_whh(const float* __restrict__ W, bf16* __restrict__ Wr) {
  size_t i = (size_t)blockIdx.x * 256 + threadIdx.x;   // 4096*1024
  int k  = (int)(i & 1023);
  int np = (int)(i >> 10);
  int T = np >> 7, w = np & 127;
  int wc = w >> 6, g = (w >> 4) & 3, hl = w & 15;
  int grow = g * HID + T * 32 + wc * 16 + hl;
  Wr[i] = __float2bfloat16(W[(size_t)grow * HID + k]);
}

// embW[v][h_col][gate] (fp32, [256][1024][4])
__global__ void k_prep_embw(const float* __restrict__ emb, const float* __restrict__ W_ih,
                            const float* __restrict__ b_ih, const float* __restrict__ b_hh,
                            float* __restrict__ embW) {
  size_t i = (size_t)blockIdx.x * 256 + threadIdx.x;   // 256*4096
  int v     = (int)(i >> 12);
  int h_col = (int)((i >> 2) & 1023);
  int g     = (int)(i & 3);
  int grow = g * HID + h_col;
  float s = b_ih[grow] + b_hh[grow];
  #pragma unroll 10
  for (int e = 0; e < EMBD; ++e)
    s += emb[(size_t)v * EMBD + e] * W_ih[(size_t)grow * EMBD + e];
  embW[i] = s;
}

__global__ void k_prep_wp(const float* __restrict__ Wp_f, bf16* __restrict__ Wp) {
  size_t i = (size_t)blockIdx.x * 256 + threadIdx.x;   // 256*1024
  Wp[i] = __float2bfloat16(Wp_f[i]);
}

__global__ void k_init_state(const float* __restrict__ h0, bf16* __restrict__ hs,
                             int* __restrict__ arr) {
  size_t i = (size_t)blockIdx.x * 256 + threadIdx.x;   // 2048*1024
  hs[i] = __float2bfloat16(h0[i]);      // h0 -> slot 0
  if (i < 16640) arr[i] = 0;            // flags [65][16] x16 pad
}

// ---------------- persistent gates kernel: 2 blocks/CU ----------------
// 512 blocks, 256 threads (4 waves, 2Mx2N), BM=128 BN=128 BK=32, ring-4 LDS
// (64 KiB -> 2 blocks/CU; co-resident block is an independent barrier domain:
// its K-loop fills this block's spin/drain/vmcnt bubbles).
// Swizzle (verified r2, 0 conflicts): slot=(4*row+g)&7 -> g ^= (row>>1)&3.
//   source-permute: (tid&3) ^ ((tid>>3)&3)  [row=tid>>2]
//   read:           kk = (q ^ ((hl>>1)&3))<<3
// B (Wr, static) prestaged BEFORE the spin -> L2/L3 latency hides under wait.
__global__ __launch_bounds__(256, 2) void g_persist(
    const float* __restrict__ c0, const bf16* __restrict__ Wr,
    bf16* __restrict__ hs, int* __restrict__ arr,
    const float* __restrict__ embW, const int* __restrict__ input,
    float* __restrict__ out, int nslots)
{
  __shared__ __align__(16) bf16 lsA[4 * 128 * 32];   // 32 KiB
  __shared__ __align__(16) bf16 lsB[4 * 128 * 32];   // 32 KiB

  const int tid  = threadIdx.x;
  const int wave = tid >> 6, lane = tid & 63;
  const int wr = wave >> 1, wc = wave & 1;
  const int hl = lane & 15, q = lane >> 4;

  const int u  = (int)blockIdx.x >> 3;
  const int by = ((int)blockIdx.x & 7) | ((u & 3) << 3);
  const int bx = u >> 2;                 // 0..15
  const int bxbase = bx * 128;

  const bf16* Bsrc = Wr + (size_t)by * 128 * HID;

  // staging: LDS granule (r,g) holds global (r, g ^ ((r>>1)&3)); dest linear.
  const size_t off0 = (size_t)(tid >> 2) * HID +
                      ((((tid & 3) ^ ((tid >> 3) & 3)) << 3));
  bf16* dA = lsA + wave * 512;   // + S*4096 (+2048 for rows 64..127)
  bf16* dB = lsB + wave * 512;

  // frag read offsets: row*32 + (q ^ ((row>>1)&3))*8 ; row%16 == hl
  const int kk = ((q ^ ((hl >> 1) & 3)) << 3);
  int aofs[4], bofs[4];
  #pragma unroll
  for (int m = 0; m < 4; ++m) aofs[m] = (wr * 64 + m * 16 + hl) * 32 + kk;
  #pragma unroll
  for (int n = 0; n < 4; ++n) bofs[n] = (wc * 64 + n * 16 + hl) * 32 + kk;

  // c-state in registers
  const int h_idx = by * 32 + wc * 16 + hl;
  float creg[4][4];
  #pragma unroll
  for (int m = 0; m < 4; ++m)
    #pragma unroll
    for (int r = 0; r < 4; ++r)
      creg[m][r] = c0[(size_t)(bxbase + wr * 64 + m * 16 + q * 4 + r) * HID + h_idx];

  const size_t slotE = (size_t)BATCH * HID;

#define STG_A(S_) { gload_lds16(pA0, dA + (S_)*4096);        pA0 += 32;  \
                    gload_lds16(pA1, dA + (S_)*4096 + 2048); pA1 += 32; }
#define STG_B(S_) { gload_lds16(pB0, dB + (S_)*4096);        pB0 += 32;  \
                    gload_lds16(pB1, dB + (S_)*4096 + 2048); pB1 += 32; }

#define MFMA16 {                                                            \
    asm volatile("s_waitcnt lgkmcnt(0)" ::: "memory");                      \
    __builtin_amdgcn_sched_barrier(0);                                      \
    __builtin_amdgcn_s_setprio(1);                                          \
    _Pragma("unroll")                                                       \
    for (int m = 0; m < 4; ++m)                                             \
      _Pragma("unroll")                                                     \
      for (int n = 0; n < 4; ++n)                                           \
        acc[m][n] = __builtin_amdgcn_mfma_f32_16x16x32_bf16(aF[m], bF[n], acc[m][n], 0, 0, 0); \
    __builtin_amdgcn_s_setprio(0);                                          \
  }

#define LOADFRAG(CUR_) \
    const bf16* Ab = lsA + (CUR_) * 4096;                                   \
    const bf16* Bb = lsB + (CUR_) * 4096;                                   \
    bf16x8 aF[4], bF[4];                                                    \
    _Pragma("unroll")                                                       \
    for (int m = 0; m < 4; ++m) aF[m] = *(const bf16x8*)(Ab + aofs[m]);     \
    _Pragma("unroll")                                                       \
    for (int n = 0; n < 4; ++n) bF[n] = *(const bf16x8*)(Bb + bofs[n]);

  for (int t = 0; t < LSEQ; ++t) {
    // B tiles 0,1: static Wr — issue BEFORE the spin (latency hides under wait)
    const bf16 *pB0 = Bsrc + off0, *pB1 = Bsrc + 64 * HID + off0;
    STG_B(0); STG_B(1);

    if (t) {
      if (tid == 0) {
        int it = 0;
        while (__hip_atomic_load(&arr[(t * 16 + bx) * 16], __ATOMIC_RELAXED,
                                 __HIP_MEMORY_SCOPE_AGENT) < 32 && ++it < (1 << 20))
          __builtin_amdgcn_s_sleep(2);
      }
      __syncthreads();
      __builtin_amdgcn_sched_barrier(0);
    }

    const bf16* Asrc = hs + (size_t)(t % nslots) * slotE + (size_t)bxbase * HID;
    const bf16 *pA0 = Asrc + off0, *pA1 = Asrc + 64 * HID + off0;

    f32x4 acc[4][4] = {};

    STG_A(0); STG_A(1);                     // in-flight: B0,B1,A0,A1 (8 loads)
    __builtin_amdgcn_sched_barrier(0);

    // tile 0 (peeled: oldest 6 = B0,B1,A0)
    {
      asm volatile("s_waitcnt vmcnt(2)" ::: "memory");
      __builtin_amdgcn_s_barrier();
      LOADFRAG(0);
      STG_A(2); STG_B(2);
      MFMA16;
    }
    // tiles 1..30
    for (int T = 1; T < 31; ++T) {
      asm volatile("s_waitcnt vmcnt(4)" ::: "memory");
      __builtin_amdgcn_s_barrier();
      const int cur = T & 3;
      LOADFRAG(cur);
      if (T < 30) { const int st = (T + 2) & 3; STG_A(st); STG_B(st); }
      MFMA16;
    }
    // tile 31 (final drain)
    {
      asm volatile("s_waitcnt vmcnt(0)" ::: "memory");
      __builtin_amdgcn_s_barrier();
      LOADFRAG(3);
      MFMA16;
    }
    __builtin_amdgcn_sched_barrier(0);

    // ---- epilogue: LSTM cell (c in regs), h -> sc0sc1 scatter ----
    bf16* hout = hs + (size_t)((t + 1) % nslots) * slotE;
    #pragma unroll
    for (int m = 0; m < 4; ++m) {
      const int b0 = bxbase + wr * 64 + m * 16 + q * 4;
      const int4 iv = *(const int4*)(input + (size_t)t * BATCH + b0);
      #pragma unroll
      for (int r = 0; r < 4; ++r) {
        const int idx = (&iv.x)[r];
        const float4 e = *(const float4*)(embW + ((size_t)idx * 1024 + h_idx) * 4);
        float gi = acc[m][0][r] + e.x;
        float gf = acc[m][1][r] + e.y;
        float gg = acc[m][2][r] + e.z;
        float go = acc[m][3][r] + e.w;
        float cn = sigf(gf) * creg[m][r] + sigf(gi) * tanh_f(gg);
        float hn = sigf(go) * tanh_f(cn);
        creg[m][r] = cn;
        const size_t off = (size_t)(b0 + r) * HID + h_idx;
        store_h_sys(hout + off, hn);
        if (t == LSEQ - 1) {
          out[(size_t)LSEQ * BATCH * VOC + off] = hn;            // hT
          out[(size_t)LSEQ * BATCH * VOC + slotE + off] = cn;    // cT
        }
      }
    }

    asm volatile("s_waitcnt vmcnt(0)" ::: "memory");   // drain asm stores
    __syncthreads();
    if (tid == 0)
      __hip_atomic_fetch_add(&arr[((t + 1) * 16 + bx) * 16], 1, __ATOMIC_RELAXED,
                             __HIP_MEMORY_SCOPE_AGENT);
  }
#undef STG_A
#undef STG_B
#undef MFMA16
#undef LOADFRAG
}

// ---------------- projection kernel (r6 structure, unchanged) ----------------
template<int MODE>
__global__ __launch_bounds__(512) void g8(
    const bf16* __restrict__ Abase, const bf16* __restrict__ Bbase,
    const float* __restrict__ b_proj, float* __restrict__ out,
    int kc, int nslots)
{
  __shared__ __align__(16) bf16 lsA[3 * 256 * 64];
  __shared__ __align__(16) bf16 lsB[3 * 128 * 64];

  const int tid  = threadIdx.x;
  const int wave = tid >> 6, lane = tid & 63;
  const int wr = wave >> 1, wc = wave & 1;
  const int hl = lane & 15, q = lane >> 4;

  const int bx = blockIdx.x, by = blockIdx.y;

  int t_local = bx >> 3;
  int slot = (kc + 1 + t_local) % nslots;
  const bf16* Asrc = Abase + ((size_t)slot * BATCH + (size_t)(bx & 7) * 256) * HID;
  const bf16* Bsrc = Bbase + (size_t)by * 128 * HID;

  const bf16 *pA0, *pA1, *pA2, *pA3, *pB0, *pB1;
  {
    int g0 = tid,      r0 = g0 >> 3, c0v = (g0 & 7) ^ (r0 & 7);
    int g1 = 512+tid,  r1 = g1 >> 3, c1v = (g1 & 7) ^ (r1 & 7);
    int g2 = 1024+tid, r2 = g2 >> 3, c2v = (g2 & 7) ^ (r2 & 7);
    int g3 = 1536+tid, r3 = g3 >> 3, c3v = (g3 & 7) ^ (r3 & 7);
    pA0 = Asrc + (size_t)r0 * HID + c0v * 8;
    pA1 = Asrc + (size_t)r1 * HID + c1v * 8;
    pA2 = Asrc + (size_t)r2 * HID + c2v * 8;
    pA3 = Asrc + (size_t)r3 * HID + c3v * 8;
    pB0 = Bsrc + (size_t)r0 * HID + c0v * 8;
    pB1 = Bsrc + (size_t)r1 * HID + c1v * 8;
  }
  bf16* dA = lsA + wave * 512;
  bf16* dB = lsB + wave * 512;

  int aofs0[4], aofs1[4], bofs0[4], bofs1[4];
  #pragma unroll
  for (int m = 0; m < 4; ++m) {
    int row = wr * 64 + m * 16 + hl;
    aofs0[m] = row * 64 + ((q ^ (hl & 7)) * 8);
    aofs1[m] = row * 64 + (((4 + q) ^ (hl & 7)) * 8);
  }
  #pragma unroll
  for (int n = 0; n < 4; ++n) {
    int row = wc * 64 + n * 16 + hl;
    bofs0[n] = row * 64 + ((q ^ (hl & 7)) * 8);
    bofs1[n] = row * 64 + (((4 + q) ^ (hl & 7)) * 8);
  }

  f32x4 acc[4][4] = {};

#define STG_P0(S_) { gload_lds16(pA0, dA + (S_)*16384);         pA0 += 64;  \
                     gload_lds16(pA1, dA + (S_)*16384 + 4096);  pA1 += 64;  \
                     gload_lds16(pA2, dA + (S_)*16384 + 8192);  pA2 += 64; }
#define STG_P1(S_) { gload_lds16(pA3, dA + (S_)*16384 + 12288); pA3 += 64;  \
                     gload_lds16(pB0, dB + (S_)*8192);          pB0 += 64;  \
                     gload_lds16(pB1, dB + (S_)*8192 + 4096);   pB1 += 64; }

#define PHASE(Ab_, Bb_, AO_, BO_, STG_) {                                   \
    bf16x8 aF[4], bF[4];                                                    \
    _Pragma("unroll")                                                       \
    for (int m = 0; m < 4; ++m) aF[m] = *(const bf16x8*)((Ab_) + AO_[m]);   \
    _Pragma("unroll")                                                       \
    for (int n = 0; n < 4; ++n) bF[n] = *(const bf16x8*)((Bb_) + BO_[n]);   \
    STG_;                                                                   \
    __builtin_amdgcn_s_barrier();                                           \
    asm volatile("s_waitcnt lgkmcnt(0)" ::: "memory");                      \
    __builtin_amdgcn_sched_barrier(0);                                      \
    __builtin_amdgcn_s_setprio(1);                                          \
    _Pragma("unroll")                                                       \
    for (int m = 0; m < 4; ++m)                                             \
      _Pragma("unroll")                                                     \
      for (int n = 0; n < 4; ++n)                                           \
        acc[m][n] = __builtin_amdgcn_mfma_f32_16x16x32_bf16(aF[m], bF[n], acc[m][n], 0, 0, 0); \
    __builtin_amdgcn_s_setprio(0);                                          \
  }

  STG_P0(0); STG_P1(0);
  STG_P0(1); STG_P1(1);
  __builtin_amdgcn_sched_barrier(0);

  int cur = 0, st = 2;
  for (int T = 0; T < 15; ++T) {
    asm volatile("s_waitcnt vmcnt(6)" ::: "memory");
    __builtin_amdgcn_s_barrier();
    const bf16* Ab = lsA + cur * 16384;
    const bf16* Bb = lsB + cur * 8192;
    if (T < 14) {
      PHASE(Ab, Bb, aofs0, bofs0, STG_P0(st));
      PHASE(Ab, Bb, aofs1, bofs1, STG_P1(st));
    } else {
      PHASE(Ab, Bb, aofs0, bofs0, );
      PHASE(Ab, Bb, aofs1, bofs1, );
    }
    cur = (cur == 2) ? 0 : cur + 1;
    st  = (st  == 2) ? 0 : st  + 1;
  }
  asm volatile("s_waitcnt vmcnt(0)" ::: "memory");
  __builtin_amdgcn_s_barrier();
  {
    const bf16* Ab = lsA + cur * 16384;
    const bf16* Bb = lsB + cur * 8192;
    PHASE(Ab, Bb, aofs0, bofs0, );
    PHASE(Ab, Bb, aofs1, bofs1, );
  }

#undef STG_P0
#undef STG_P1
#undef PHASE

  const int qrow = q * 4;
  const int t_glob = kc + (bx >> 3);
  float* os = out + (size_t)t_glob * BATCH * VOC;
  const int b0base = (bx & 7) * 256 + wr * 64;
  #pragma unroll
  for (int m = 0; m < 4; ++m) {
    #pragma unroll
    for (int n = 0; n < 4; ++n) {
      const int v = by * 128 + wc * 64 + n * 16 + hl;
      const float bp = b_proj[v];
      #pragma unroll
      for (int r = 0; r < 4; ++r)
        os[(size_t)(b0base + m * 16 + qrow + r) * VOC + v] = acc[m][n][r] + bp;
    }
  }
}

// ---------------- host ----------------

extern "C" void kernel_launch(void* const* d_in, const int* in_sizes, int n_in,
                              void* d_out, int out_size, void* d_ws, size_t ws_size,
                              hipStream_t stream)
{
  (void)in_sizes; (void)n_in; (void)out_size; (void)ws_size;
  const int*   input  = (const int*)  d_in[0];
  const float* h0     = (const float*)d_in[1];
  const float* c0     = (const float*)d_in[2];
  const float* emb    = (const float*)d_in[3];
  const float* W_ih   = (const float*)d_in[4];
  const float* W_hh   = (const float*)d_in[5];
  const float* b_ih   = (const float*)d_in[6];
  const float* b_hh   = (const float*)d_in[7];
  const float* W_proj = (const float*)d_in[8];
  const float* b_proj = (const float*)d_in[9];
  float* out = (float*)d_out;

  char* ws = (char*)d_ws;
  bf16*  Wr   = (bf16*)(ws);               //  8,388,608 B
  bf16*  Wp   = (bf16*)(ws + 8388608);     //    524,288 B
  float* embW = (float*)(ws + 8912896);    //  4,194,304 B
  int*   arr  = (int*)  (ws + 13107200);   //  16640 ints = 66,560 B
  bf16*  hs   = (bf16*) (ws + 13173760);   //  65 * 4,194,304 B
  const int nslots = 65;

  k_prep_whh <<<16384, 256, 0, stream>>>(W_hh, Wr);
  k_prep_wp  <<<1024,  256, 0, stream>>>(W_proj, Wp);
  k_prep_embw<<<4096,  256, 0, stream>>>(emb, W_ih, b_ih, b_hh, embW);
  k_init_state<<<8192, 256, 0, stream>>>(h0, hs, arr);

  g_persist<<<dim3(512), 256, 0, stream>>>(c0, Wr, hs, arr, embW, input, out, nslots);

  g8<1><<<dim3(8 * 64, 2), 512, 0, stream>>>(hs, Wp, b_proj, out, 0, nslots);
}

// Round 10
// 1893.457 us; speedup vs baseline: 1.3202x; 1.3202x over previous
//
#include <hip/hip_runtime.h>
#include <hip/hip_bf16.h>
#include <cstdint>
#include <cstddef>

#define LSEQ  64
#define BATCH 2048
#define HID   1024
#define NGATE 4096
#define VOC   256
#define EMBD  50

using bf16 = __hip_bfloat16;
typedef __attribute__((ext_vector_type(8))) __bf16 bf16x8;
typedef __attribute__((ext_vector_type(4))) float  f32x4;

__device__ __forceinline__ void gload_lds16(const void* g, void* l) {
  __builtin_amdgcn_global_load_lds(
      (const __attribute__((address_space(1))) unsigned int*)g,
      (__attribute__((address_space(3))) unsigned int*)l, 16, 0, 0);
}

__device__ __forceinline__ float sigf(float x) {
  x = fminf(fmaxf(x, -30.f), 30.f);
  return 1.f / (1.f + __expf(-x));
}
__device__ __forceinline__ float tanh_f(float x) {
  x = fminf(fmaxf(x, -15.f), 15.f);
  float e = __expf(2.f * x);
  return (e - 1.f) / (e + 1.f);
}

// ---------------- setup kernels ----------------

__global__ void k_prep_whh(const float* __restrict__ W, bf16* __restrict__ Wr) {
  size_t i = (size_t)blockIdx.x * 256 + threadIdx.x;   // 4096*1024
  int k  = (int)(i & 1023);
  int np = (int)(i >> 10);
  int T = np >> 7, w = np & 127;
  int wc = w >> 6, g = (w >> 4) & 3, hl = w & 15;
  int grow = g * HID + T * 32 + wc * 16 + hl;
  Wr[i] = __float2bfloat16(W[(size_t)grow * HID + k]);
}

// embW[v][h_col][gate] (fp32, [256][1024][4])
__global__ void k_prep_embw(const float* __restrict__ emb, const float* __restrict__ W_ih,
                            const float* __restrict__ b_ih, const float* __restrict__ b_hh,
                            float* __restrict__ embW) {
  size_t i = (size_t)blockIdx.x * 256 + threadIdx.x;   // 256*4096
  int v     = (int)(i >> 12);
  int h_col = (int)((i >> 2) & 1023);
  int g     = (int)(i & 3);
  int grow = g * HID + h_col;
  float s = b_ih[grow] + b_hh[grow];
  #pragma unroll 10
  for (int e = 0; e < EMBD; ++e)
    s += emb[(size_t)v * EMBD + e] * W_ih[(size_t)grow * EMBD + e];
  embW[i] = s;
}

__global__ void k_prep_wp(const float* __restrict__ Wp_f, bf16* __restrict__ Wp) {
  size_t i = (size_t)blockIdx.x * 256 + threadIdx.x;   // 256*1024
  Wp[i] = __float2bfloat16(Wp_f[i]);
}

__global__ void k_init_state(const float* __restrict__ h0, const float* __restrict__ c0,
                             bf16* __restrict__ hs, float* __restrict__ cb) {
  size_t i = (size_t)blockIdx.x * 256 + threadIdx.x;   // 2048*1024
  hs[i] = __float2bfloat16(h0[i]);      // h0 -> slot 0
  cb[i] = c0[i];
}

// ---------------- launched GEMM kernel (r3 skeleton, 1-barrier tile loop) ----
// BM=256, BN=128, BK=64, 512 threads (8 waves, 4M x 2N), LDS ring-3 of K-tiles.
// Per K-tile: {vmcnt(6); s_barrier; STG6(T+2); 16 ds_read (both phases);
//              MFMA p0 (compiler lgkm-counted); MFMA p1}.
// WAR safety: stage(T+2) is issued only after entry barrier T; any wave past
// barrier T+1 implies all waves' tile-T ds_reads completed (program order).
template<int MODE>
__global__ __launch_bounds__(512) void g8(
    const bf16* __restrict__ Abase, const bf16* __restrict__ Bbase,
    const float* __restrict__ c_in, float* __restrict__ c_out,
    bf16* __restrict__ h_out,
    const float* __restrict__ embW, const int* __restrict__ input,
    const float* __restrict__ b_proj, float* __restrict__ out,
    int t, int kc, int nslots)
{
  __shared__ __align__(16) bf16 lsA[3 * 256 * 64];   // 96 KiB
  __shared__ __align__(16) bf16 lsB[3 * 128 * 64];   // 48 KiB

  const int tid  = threadIdx.x;
  const int wave = tid >> 6, lane = tid & 63;
  const int wr = wave >> 1, wc = wave & 1;
  const int hl = lane & 15, q = lane >> 4;

  int bx, by;
  if constexpr (MODE == 0) {
    // XCD-aware (r3-proven): each XCD re-reads only 4 Wr panels (1MB, L2-hot)
    int id = blockIdx.x, xcd = id & 7, idx = id >> 3;
    by = xcd + ((idx & 3) << 3);
    bx = idx >> 2;
  } else {
    bx = blockIdx.x; by = blockIdx.y;
  }

  const bf16* Asrc;
  if constexpr (MODE == 0) {
    Asrc = Abase + (size_t)bx * 256 * HID;
  } else {
    int t_local = bx >> 3;
    int slot = (kc + 1 + t_local) % nslots;
    Asrc = Abase + ((size_t)slot * BATCH + (size_t)(bx & 7) * 256) * HID;
  }
  const bf16* Bsrc = Bbase + (size_t)by * 128 * HID;

  // staging source pointers: LDS granule (row,gl) holds global (row, gl^(row&7))
  const bf16 *pA0, *pA1, *pA2, *pA3, *pB0, *pB1;
  {
    int g0 = tid,      r0 = g0 >> 3, c0v = (g0 & 7) ^ (r0 & 7);
    int g1 = 512+tid,  r1 = g1 >> 3, c1v = (g1 & 7) ^ (r1 & 7);
    int g2 = 1024+tid, r2 = g2 >> 3, c2v = (g2 & 7) ^ (r2 & 7);
    int g3 = 1536+tid, r3 = g3 >> 3, c3v = (g3 & 7) ^ (r3 & 7);
    pA0 = Asrc + (size_t)r0 * HID + c0v * 8;
    pA1 = Asrc + (size_t)r1 * HID + c1v * 8;
    pA2 = Asrc + (size_t)r2 * HID + c2v * 8;
    pA3 = Asrc + (size_t)r3 * HID + c3v * 8;
    pB0 = Bsrc + (size_t)r0 * HID + c0v * 8;
    pB1 = Bsrc + (size_t)r1 * HID + c1v * 8;
  }
  bf16* dA = lsA + wave * 512;
  bf16* dB = lsB + wave * 512;

  // frag read offsets (row*64 + (g ^ (row&7))*8), g = ks*4 + q
  int aofs0[4], aofs1[4], bofs0[4], bofs1[4];
  #pragma unroll
  for (int m = 0; m < 4; ++m) {
    int row = wr * 64 + m * 16 + hl;
    aofs0[m] = row * 64 + ((q ^ (hl & 7)) * 8);
    aofs1[m] = row * 64 + (((4 + q) ^ (hl & 7)) * 8);
  }
  #pragma unroll
  for (int n = 0; n < 4; ++n) {
    int row = wc * 64 + n * 16 + hl;
    bofs0[n] = row * 64 + ((q ^ (hl & 7)) * 8);
    bofs1[n] = row * 64 + (((4 + q) ^ (hl & 7)) * 8);
  }

  f32x4 acc[4][4] = {};

#define STG6(S_) { gload_lds16(pA0, dA + (S_)*16384);         pA0 += 64;  \
                   gload_lds16(pA1, dA + (S_)*16384 + 4096);  pA1 += 64;  \
                   gload_lds16(pA2, dA + (S_)*16384 + 8192);  pA2 += 64;  \
                   gload_lds16(pA3, dA + (S_)*16384 + 12288); pA3 += 64;  \
                   gload_lds16(pB0, dB + (S_)*8192);          pB0 += 64;  \
                   gload_lds16(pB1, dB + (S_)*8192 + 4096);   pB1 += 64; }

#define KTILE(S_, DOST_, ST_) {                                             \
    const bf16* Ab = lsA + (S_) * 16384;                                    \
    const bf16* Bb = lsB + (S_) * 8192;                                     \
    if (DOST_) STG6(ST_);                                                   \
    bf16x8 a0[4], b0[4], a1[4], b1[4];                                      \
    _Pragma("unroll")                                                       \
    for (int m = 0; m < 4; ++m) { a0[m] = *(const bf16x8*)(Ab + aofs0[m]);  \
                                  a1[m] = *(const bf16x8*)(Ab + aofs1[m]); }\
    _Pragma("unroll")                                                       \
    for (int n = 0; n < 4; ++n) { b0[n] = *(const bf16x8*)(Bb + bofs0[n]);  \
                                  b1[n] = *(const bf16x8*)(Bb + bofs1[n]); }\
    __builtin_amdgcn_sched_barrier(0);                                      \
    __builtin_amdgcn_s_setprio(1);                                          \
    _Pragma("unroll")                                                       \
    for (int m = 0; m < 4; ++m)                                             \
      _Pragma("unroll")                                                     \
      for (int n = 0; n < 4; ++n)                                           \
        acc[m][n] = __builtin_amdgcn_mfma_f32_16x16x32_bf16(a0[m], b0[n], acc[m][n], 0, 0, 0); \
    __builtin_amdgcn_s_setprio(0);                                          \
    __builtin_amdgcn_sched_barrier(0);                                      \
    __builtin_amdgcn_s_setprio(1);                                          \
    _Pragma("unroll")                                                       \
    for (int m = 0; m < 4; ++m)                                             \
      _Pragma("unroll")                                                     \
      for (int n = 0; n < 4; ++n)                                           \
        acc[m][n] = __builtin_amdgcn_mfma_f32_16x16x32_bf16(a1[m], b1[n], acc[m][n], 0, 0, 0); \
    __builtin_amdgcn_s_setprio(0);                                          \
  }

#define WAIT6 { asm volatile("s_waitcnt vmcnt(6)" ::: "memory"); __builtin_amdgcn_s_barrier(); }

  // prologue: stage K-tiles 0,1
  STG6(0); STG6(1);
  __builtin_amdgcn_sched_barrier(0);

  #pragma unroll 1
  for (int Tq = 0; Tq < 4; ++Tq) {       // tiles 0..11
    WAIT6; KTILE(0, 1, 2);
    WAIT6; KTILE(1, 1, 0);
    WAIT6; KTILE(2, 1, 1);
  }
  WAIT6; KTILE(0, 1, 2);                 // T=12, stages 14
  WAIT6; KTILE(1, 1, 0);                 // T=13, stages 15
  WAIT6; KTILE(2, 0, 0);                 // T=14
  { asm volatile("s_waitcnt vmcnt(0)" ::: "memory"); __builtin_amdgcn_s_barrier(); }
  KTILE(0, 0, 0);                        // T=15
  __builtin_amdgcn_sched_barrier(0);

#undef STG6
#undef KTILE
#undef WAIT6

  const int qrow = q * 4;

  if constexpr (MODE == 0) {
    const int h_idx = by * 32 + wc * 16 + hl;
    #pragma unroll
    for (int m = 0; m < 4; ++m) {
      const int b0 = bx * 256 + wr * 64 + m * 16 + qrow;
      const int4 iv = *(const int4*)(input + (size_t)t * BATCH + b0);
      #pragma unroll
      for (int r = 0; r < 4; ++r) {
        const int idx = (&iv.x)[r];
        const float4 e = *(const float4*)(embW + ((size_t)idx * 1024 + h_idx) * 4);
        float gi = acc[m][0][r] + e.x;
        float gf = acc[m][1][r] + e.y;
        float gg = acc[m][2][r] + e.z;
        float go = acc[m][3][r] + e.w;
        const size_t off = (size_t)(b0 + r) * HID + h_idx;
        float cn = sigf(gf) * c_in[off] + sigf(gi) * tanh_f(gg);
        float hn = sigf(go) * tanh_f(cn);
        h_out[off] = __float2bfloat16(hn);
        c_out[off] = cn;
        if (t == LSEQ - 1) {
          out[(size_t)LSEQ * BATCH * VOC + off] = hn;                          // hT
          out[(size_t)LSEQ * BATCH * VOC + (size_t)BATCH * HID + off] = cn;    // cT
        }
      }
    }
  } else {
    const int t_glob = kc + (bx >> 3);
    float* os = out + (size_t)t_glob * BATCH * VOC;
    const int b0base = (bx & 7) * 256 + wr * 64;
    #pragma unroll
    for (int m = 0; m < 4; ++m) {
      #pragma unroll
      for (int n = 0; n < 4; ++n) {
        const int v = by * 128 + wc * 64 + n * 16 + hl;
        const float bp = b_proj[v];
        #pragma unroll
        for (int r = 0; r < 4; ++r)
          os[(size_t)(b0base + m * 16 + qrow + r) * VOC + v] = acc[m][n][r] + bp;
      }
    }
  }
}

// ---------------- host ----------------

extern "C" void kernel_launch(void* const* d_in, const int* in_sizes, int n_in,
                              void* d_out, int out_size, void* d_ws, size_t ws_size,
                              hipStream_t stream)
{
  (void)in_sizes; (void)n_in; (void)out_size; (void)ws_size;
  const int*   input  = (const int*)  d_in[0];
  const float* h0     = (const float*)d_in[1];
  const float* c0     = (const float*)d_in[2];
  const float* emb    = (const float*)d_in[3];
  const float* W_ih   = (const float*)d_in[4];
  const float* W_hh   = (const float*)d_in[5];
  const float* b_ih   = (const float*)d_in[6];
  const float* b_hh   = (const float*)d_in[7];
  const float* W_proj = (const float*)d_in[8];
  const float* b_proj = (const float*)d_in[9];
  float* out = (float*)d_out;

  char* ws = (char*)d_ws;
  bf16*  Wr   = (bf16*)(ws);               //  8,388,608 B
  bf16*  Wp   = (bf16*)(ws + 8388608);     //    524,288 B
  float* embW = (float*)(ws + 8912896);    //  4,194,304 B
  float* cb0  = (float*)(ws + 13107200);   //  8,388,608 B
  float* cb1  = (float*)(ws + 21495808);   //  8,388,608 B
  bf16*  hs   = (bf16*) (ws + 29884416);   //  65 * 4,194,304 B
  const int nslots = 65;
  const int chunk  = 16;

  k_prep_whh <<<16384, 256, 0, stream>>>(W_hh, Wr);
  k_prep_wp  <<<1024,  256, 0, stream>>>(W_proj, Wp);
  k_prep_embw<<<4096,  256, 0, stream>>>(emb, W_ih, b_ih, b_hh, embW);
  k_init_state<<<8192, 256, 0, stream>>>(h0, c0, hs, cb0);   // h0 -> slot 0

  float* cbuf[2] = {cb0, cb1};
  for (int kc = 0; kc < LSEQ; kc += chunk) {
    for (int t = kc; t < kc + chunk; ++t) {
      g8<0><<<dim3(256), 512, 0, stream>>>(
          hs + (size_t)(t % nslots) * BATCH * HID, Wr,
          cbuf[t & 1], cbuf[(t + 1) & 1],
          hs + (size_t)((t + 1) % nslots) * BATCH * HID,
          embW, input, b_proj, out, t, 0, 0);
    }
    // project h for steps kc..kc+chunk-1 while those slots are L2/L3-hot
    g8<1><<<dim3(8 * chunk, 2), 512, 0, stream>>>(
        hs, Wp, nullptr, nullptr, nullptr,
        nullptr, nullptr, b_proj, out, 0, kc, nslots);
  }
}